// Round 1
// baseline (142.186 us; speedup 1.0000x reference)
//
#include <hip/hip_runtime.h>
#include <hip/hip_bf16.h>

// VarFlowLoss on MI355X (gfx950)
// Stages:
//   k_zero      : zero the scalar output
//   k_weights   : W_att [64][256][9] -> WT1 [9][64][256] bf16 ; W_post -> WT2 [9][16][64] bf16 (od padded)
//   k_transpose : feat NCHW fp32 -> featT [B*4096][256] bf16 ; depth -> depthT [B*4096][64] bf16
//   k_borders   : per-8x8-patch border log-sums -> S[131072] float4 {Sn,Ss,Sw,Se}
//   k_gemm1     : att = sigmoid(conv3x3(feat,W_att)+b) ; adT = att*depth (bf16, in-place over depthT)
//   k_gemm2     : ds = conv3x3(ad,W_post)+b ; fused smooth_l1 vs flow ; block-reduce ; atomicAdd
// ws usage: featT 67.1MB + depthT/adT 16.8MB + WT1 0.29MB + WT2 18KB + S 2MB = ~86.3MB

typedef __attribute__((ext_vector_type(4))) float f32x4;
typedef __attribute__((ext_vector_type(8))) short s16x8;

#define DEVFN __device__ __forceinline__

DEVFN float bf2f(unsigned short u){
  unsigned int x = ((unsigned int)u) << 16;
  float f; __builtin_memcpy(&f, &x, 4); return f;
}
DEVFN unsigned short f2bf(float f){
  unsigned int x; __builtin_memcpy(&x, &f, 4);
  x += 0x7fffu + ((x >> 16) & 1u);   // RNE
  return (unsigned short)(x >> 16);
}

#define ASYNC16(gp, lp) __builtin_amdgcn_global_load_lds( \
    (const __attribute__((address_space(1))) unsigned int*)(gp), \
    (__attribute__((address_space(3))) unsigned int*)(lp), 16, 0, 0)

__global__ void k_zero(float* o){ *o = 0.0f; }

// ---------------- weights transform ----------------
__global__ void k_weights(const float* __restrict__ Watt, const float* __restrict__ Wpost,
                          unsigned short* __restrict__ WT1, unsigned short* __restrict__ WT2){
  const int t = blockIdx.x * 256 + threadIdx.x;
  const int n1 = 9 * 64 * 256;
  if (t < n1){
    const int tap = t / (64 * 256);
    const int rem = t % (64 * 256);
    const int oc = rem / 256, ic = rem % 256;
    WT1[t] = f2bf(Watt[(oc * 256 + ic) * 9 + tap]);
  }
  const int n2 = 9 * 16 * 64;
  if (t < n2){
    const int tap = t / (16 * 64);
    const int rem = t % (16 * 64);
    const int od = rem / 64, ic = rem % 64;
    const float v = (od < 10) ? Wpost[(od * 64 + ic) * 9 + tap] : 0.0f;
    WT2[t] = f2bf(v);
  }
}

// ---------------- NCHW fp32 -> [B*H*W][C] bf16 transpose ----------------
template<int C, int CH>
__global__ void k_transpose(const float* __restrict__ src, unsigned short* __restrict__ dst){
  constexpr int NCH = C / CH;
  const int bid = blockIdx.x;
  const int cg = bid % NCH;
  const int y  = (bid / NCH) % 64;
  const int b  = bid / (NCH * 64);
  __shared__ float lds[CH][65];
  const int t = threadIdx.x;
  const int x = t & 63, rg = t >> 6;
  const float* sp = src + ((size_t)b * C + (size_t)cg * CH) * 4096 + (size_t)y * 64;
#pragma unroll
  for (int r = rg; r < CH; r += 4) lds[r][x] = sp[(size_t)r * 4096 + x];
  __syncthreads();
  constexpr int PT = CH / 4;
  const int ox = t >> 2;
  const int oc0 = (t & 3) * PT;
  unsigned short* dp = dst + ((size_t)b * 4096 + (size_t)y * 64 + ox) * C + cg * CH + oc0;
#pragma unroll
  for (int k = 0; k < PT; k += 8){
    s16x8 v;
#pragma unroll
    for (int j = 0; j < 8; ++j) v[j] = (short)f2bf(lds[oc0 + k + j][ox]);
    *(s16x8*)(dp + k) = v;
  }
}

// ---------------- patch border log-sums ----------------
__global__ void k_borders(const float* __restrict__ gts, float* __restrict__ S){
  const int t = blockIdx.x * 256 + threadIdx.x;   // patch id: (b*64+py)*64+px
  const int px = t & 63, py = (t >> 6) & 63, b = t >> 12;
  const float* base = gts + (size_t)b * 262144 + (size_t)py * 8 * 512 + (size_t)px * 8;
  float sn = 0.f, ss = 0.f, sw = 0.f, se = 0.f;
#pragma unroll
  for (int i = 0; i < 8; ++i){
    const float vn = base[i];
    const float vs = base[7 * 512 + i];
    const float vw = base[i * 512];
    const float ve = base[i * 512 + 7];
    sn += logf(((vn > 0.1f) && (vn < 80.f) ? vn : 0.f) + 1e-6f);
    ss += logf(((vs > 0.1f) && (vs < 80.f) ? vs : 0.f) + 1e-6f);
    sw += logf(((vw > 0.1f) && (vw < 80.f) ? vw : 0.f) + 1e-6f);
    se += logf(((ve > 0.1f) && (ve < 80.f) ? ve : 0.f) + 1e-6f);
  }
  f32x4 v = {sn, ss, sw, se};
  *(f32x4*)(S + (size_t)t * 4) = v;
}

// ---------------- GEMM1: att conv + sigmoid*depth ----------------
// block: (b, ytile) -> 256 output rows (4 y-rows x 64 x), all 64 oc.
// A window in LDS: 6 y-rows (384 m-rows) x 32-ic chunk. B: all 9 taps x 64 oc x 32 ic.
__global__ __launch_bounds__(256, 2) void k_gemm1(
    const unsigned short* __restrict__ featT,   // [B*4096][256]
    const unsigned short* __restrict__ WT1,     // [9][64][256]
    const float* __restrict__ batt,
    unsigned short* __restrict__ ad)            // in: depthT, out: adT  [B*4096][64]
{
  __shared__ unsigned short As[384 * 32];
  __shared__ unsigned short Bs[576 * 32];
  const int t = threadIdx.x;
  const int l = t & 63, w = t >> 6;
  const int bid = blockIdx.x;
  const int b = bid >> 4, ytile = bid & 15;
  const int y0 = ytile * 4;
  const int fr = l & 15, g = l >> 4;

  f32x4 acc[4][4];
#pragma unroll
  for (int i = 0; i < 4; ++i)
#pragma unroll
    for (int j = 0; j < 4; ++j)
#pragma unroll
      for (int q = 0; q < 4; ++q) acc[i][j][q] = 0.0f;

  for (int c = 0; c < 8; ++c){
    // stage A: 6 y-rows (one per iteration; uniform validity per iteration)
#pragma unroll
    for (int it = 0; it < 6; ++it){
      const int yy = y0 - 1 + it;
      unsigned short* lp = &As[(it * 64 + (t >> 2)) * 32 + (t & 3) * 8];
      if (yy >= 0 && yy < 64){
        const unsigned short* gp = featT
            + ((size_t)b * 4096 + (size_t)yy * 64 + (t >> 2)) * 256 + c * 32 + (t & 3) * 8;
        ASYNC16(gp, lp);
      } else {
        s16x8 z = {0,0,0,0,0,0,0,0};
        *(s16x8*)lp = z;
      }
    }
    // stage B: 576 rows x 64B = 2304 16B chunks
#pragma unroll
    for (int it = 0; it < 9; ++it){
      const int idx = it * 256 + t;
      const int row = idx >> 2;
      const unsigned short* gp = WT1 + (size_t)row * 256 + c * 32 + (idx & 3) * 8;
      ASYNC16(gp, &Bs[row * 32 + (idx & 3) * 8]);
    }
    __syncthreads();

    for (int tap = 0; tap < 9; ++tap){
      const int dy = tap / 3 - 1, dx = tap % 3 - 1;
      s16x8 af[4], bfr[4];
#pragma unroll
      for (int i = 0; i < 4; ++i){
        const int x = i * 16 + fr;          // output x of this fragment row (wave-independent)
        const int xv = x + dx;
        const bool valid = (xv >= 0) && (xv < 64);
        int wr = w * 64 + i * 16 + fr + (dy + 1) * 64 + dx;
        wr = valid ? wr : 0;
        s16x8 v = *(const s16x8*)&As[wr * 32 + g * 8];
        s16x8 z = {0,0,0,0,0,0,0,0};
        af[i] = valid ? v : z;
      }
#pragma unroll
      for (int j = 0; j < 4; ++j)
        bfr[j] = *(const s16x8*)&Bs[(tap * 64 + j * 16 + fr) * 32 + g * 8];
#pragma unroll
      for (int i = 0; i < 4; ++i)
#pragma unroll
        for (int j = 0; j < 4; ++j)
          acc[i][j] = __builtin_amdgcn_mfma_f32_16x16x32_bf16(af[i], bfr[j], acc[i][j], 0, 0, 0);
    }
    __syncthreads();
  }

  // epilogue: att = sigmoid(acc + b); ad = att * depth (in place)
#pragma unroll
  for (int i = 0; i < 4; ++i){
#pragma unroll
    for (int q = 0; q < 4; ++q){
      const int r = w * 64 + i * 16 + g * 4 + q;
      const int y = y0 + (r >> 6), x = r & 63;
      const size_t gm = (size_t)b * 4096 + (size_t)y * 64 + x;
#pragma unroll
      for (int j = 0; j < 4; ++j){
        const int oc = j * 16 + fr;
        const float v = acc[i][j][q] + batt[oc];
        const float att = 1.0f / (1.0f + __expf(-v));
        const size_t idx = gm * 64 + oc;
        ad[idx] = f2bf(att * bf2f(ad[idx]));
      }
    }
  }
}

// ---------------- GEMM2: post conv + fused smooth-L1 loss ----------------
DEVFN float sel4(f32x4 v, int i){
  const float ab = (i & 1) ? v[1] : v[0];
  const float cd = (i & 1) ? v[3] : v[2];
  return (i & 2) ? cd : ab;
}

__global__ __launch_bounds__(256, 2) void k_gemm2(
    const unsigned short* __restrict__ ad,      // [B*4096][64]
    const unsigned short* __restrict__ WT2,     // [9][16][64]
    const float* __restrict__ bpost,
    const f32x4* __restrict__ S,                // [B*4096] {Sn,Ss,Sw,Se}
    float* __restrict__ out)
{
  __shared__ unsigned short As[384 * 32];
  __shared__ unsigned short Bs[144 * 32];
  __shared__ float ps[4];
  const int t = threadIdx.x;
  const int l = t & 63, w = t >> 6;
  const int bid = blockIdx.x;
  const int b = bid >> 4, ytile = bid & 15;
  const int y0 = ytile * 4;
  const int fr = l & 15, g = l >> 4;

  f32x4 acc[4];
#pragma unroll
  for (int i = 0; i < 4; ++i)
#pragma unroll
    for (int q = 0; q < 4; ++q) acc[i][q] = 0.0f;

  for (int c = 0; c < 2; ++c){
#pragma unroll
    for (int it = 0; it < 6; ++it){
      const int yy = y0 - 1 + it;
      unsigned short* lp = &As[(it * 64 + (t >> 2)) * 32 + (t & 3) * 8];
      if (yy >= 0 && yy < 64){
        const unsigned short* gp = ad
            + ((size_t)b * 4096 + (size_t)yy * 64 + (t >> 2)) * 64 + c * 32 + (t & 3) * 8;
        ASYNC16(gp, lp);
      } else {
        s16x8 z = {0,0,0,0,0,0,0,0};
        *(s16x8*)lp = z;
      }
    }
#pragma unroll
    for (int it = 0; it < 3; ++it){
      const int idx = it * 256 + t;
      if (idx < 576){
        const int row = idx >> 2;
        const unsigned short* gp = WT2 + (size_t)row * 64 + c * 32 + (idx & 3) * 8;
        ASYNC16(gp, &Bs[row * 32 + (idx & 3) * 8]);
      }
    }
    __syncthreads();

    for (int tap = 0; tap < 9; ++tap){
      const int dy = tap / 3 - 1, dx = tap % 3 - 1;
      s16x8 af[4];
#pragma unroll
      for (int i = 0; i < 4; ++i){
        const int x = i * 16 + fr;
        const int xv = x + dx;
        const bool valid = (xv >= 0) && (xv < 64);
        int wr = w * 64 + i * 16 + fr + (dy + 1) * 64 + dx;
        wr = valid ? wr : 0;
        s16x8 v = *(const s16x8*)&As[wr * 32 + g * 8];
        s16x8 z = {0,0,0,0,0,0,0,0};
        af[i] = valid ? v : z;
      }
      s16x8 bfr = *(const s16x8*)&Bs[(tap * 16 + fr) * 32 + g * 8];
#pragma unroll
      for (int i = 0; i < 4; ++i)
        acc[i] = __builtin_amdgcn_mfma_f32_16x16x32_bf16(af[i], bfr, acc[i], 0, 0, 0);
    }
    __syncthreads();
  }

  // fused loss epilogue
  // od -> which border sum (0:n 1:s 2:w 3:e); even od shift in x, odd od shift in y
  const unsigned aPack = (3u<<0)|(1u<<2)|(3u<<4)|(1u<<6)|(2u<<8)|(0u<<10)|(1u<<12)|(3u<<14)|(0u<<16)|(2u<<18);
  const unsigned bPack = (2u<<0)|(0u<<2)|(3u<<4)|(1u<<6)|(2u<<8)|(0u<<10)|(1u<<12)|(3u<<14)|(0u<<16)|(2u<<18);
  float lsum = 0.0f;
  if (fr < 10){
    const int od = fr;
    const int ai = (aPack >> (2 * od)) & 3;
    const int bi = (bPack >> (2 * od)) & 3;
    const bool xshift = (od & 1) == 0;
    const float bp = bpost[od];
#pragma unroll
    for (int i = 0; i < 4; ++i){
#pragma unroll
      for (int q = 0; q < 4; ++q){
        const int r = w * 64 + i * 16 + g * 4 + q;
        const int y = y0 + (r >> 6), x = r & 63;
        const size_t gm = (size_t)b * 4096 + (size_t)y * 64 + x;
        const f32x4 sa = S[gm];
        const bool nb = xshift ? (x < 63) : (y < 63);
        const size_t ga = xshift ? (nb ? gm + 1 : gm) : (nb ? gm + 64 : gm);
        const f32x4 sbv = S[ga];
        const float sbf = nb ? sel4(sbv, bi) : 0.0f;
        const float flow = (sel4(sa, ai) - sbf) * 0.125f;
        const float dv = acc[i][q] + bp - flow;
        const float adv = fabsf(dv);
        lsum += (adv < 0.01f) ? (50.0f * dv * dv) : (adv - 0.005f);
      }
    }
  }
#pragma unroll
  for (int off = 32; off > 0; off >>= 1) lsum += __shfl_down(lsum, off);
  if (l == 0) ps[w] = lsum;
  __syncthreads();
  if (t == 0) atomicAdd(out, (ps[0] + ps[1] + ps[2] + ps[3]) * (1.0f / 1310720.0f));
}

// ---------------- launch ----------------
extern "C" void kernel_launch(void* const* d_in, const int* in_sizes, int n_in,
                              void* d_out, int out_size, void* d_ws, size_t ws_size,
                              hipStream_t stream){
  const float* feat  = (const float*)d_in[0];
  const float* depth = (const float*)d_in[1];
  const float* gts   = (const float*)d_in[2];
  const float* Watt  = (const float*)d_in[3];
  const float* batt  = (const float*)d_in[4];
  const float* Wpost = (const float*)d_in[5];
  const float* bpost = (const float*)d_in[6];
  float* out = (float*)d_out;
  char* ws = (char*)d_ws;

  unsigned short* featT = (unsigned short*)ws;                                   // 67108864 B
  unsigned short* adT   = (unsigned short*)(ws + 67108864);                      // 16777216 B
  unsigned short* WT1   = (unsigned short*)(ws + 67108864 + 16777216);           // 294912 B
  unsigned short* WT2   = (unsigned short*)(ws + 67108864 + 16777216 + 294912);  // 18432 B
  float*          S     = (float*)(ws + 67108864 + 16777216 + 294912 + 18432);   // 2097152 B

  k_zero<<<1, 1, 0, stream>>>(out);
  k_weights<<<576, 256, 0, stream>>>(Watt, Wpost, WT1, WT2);
  k_transpose<256, 128><<<32 * 64 * 2, 256, 0, stream>>>(feat, featT);
  k_transpose<64, 64><<<32 * 64, 256, 0, stream>>>(depth, adT);
  k_borders<<<512, 256, 0, stream>>>(gts, S);
  k_gemm1<<<512, 256, 0, stream>>>(featT, WT1, batt, adT);
  k_gemm2<<<512, 256, 0, stream>>>(adT, WT2, bpost, (const f32x4*)S, out);
}

// Round 2
// 122.045 us; speedup vs baseline: 1.1650x; 1.1650x over previous
//
#include <hip/hip_runtime.h>
#include <hip/hip_bf16.h>

// VarFlowLoss on MI355X (gfx950) — round 2
//   k_prep      : out=0 ; weights -> WT1/WT2 bf16 ; slab-coalesced patch border log-sums -> S
//   k_transpose : feat NCHW fp32 -> featT [B*4096][256] bf16 (64B-line writes)
//   k_gemm1     : 2-phase prefetch dbuf conv GEMM (BM=512, 8 waves, 152KB LDS)
//                 epilogue: att=sigmoid(.); adT = att * depth (depth read NCHW directly)
//   k_gemm2     : post conv + fused smooth-L1 loss (BM=512, dbuf A, resident B)

typedef __attribute__((ext_vector_type(4))) float f32x4;
typedef __attribute__((ext_vector_type(8))) short s16x8;

#define DEVFN __device__ __forceinline__

DEVFN float bf2f(unsigned short u){
  unsigned int x = ((unsigned int)u) << 16;
  float f; __builtin_memcpy(&f, &x, 4); return f;
}
DEVFN unsigned short f2bf(float f){
  unsigned int x; __builtin_memcpy(&x, &f, 4);
  x += 0x7fffu + ((x >> 16) & 1u);   // RNE
  return (unsigned short)(x >> 16);
}

#define ASYNC16(gp, lp) __builtin_amdgcn_global_load_lds( \
    (const __attribute__((address_space(1))) unsigned int*)(gp), \
    (__attribute__((address_space(3))) unsigned int*)(lp), 16, 0, 0)

// ---------------- prep: zero + weights + borders ----------------
__global__ void k_prep(const float* __restrict__ Watt, const float* __restrict__ Wpost,
                       const float* __restrict__ gts,
                       unsigned short* __restrict__ WT1, unsigned short* __restrict__ WT2,
                       float* __restrict__ S, float* __restrict__ out){
  const int bid = blockIdx.x, tid = threadIdx.x;
  if (bid == 0){
    if (tid == 0) *out = 0.0f;
    return;
  }
  if (bid <= 576){
    const int t = (bid - 1) * 256 + tid;
    const int n1 = 9 * 64 * 256;
    if (t < n1){
      const int tap = t / (64 * 256);
      const int rem = t % (64 * 256);
      const int oc = rem / 256, ic = rem % 256;
      WT1[t] = f2bf(Watt[(oc * 256 + ic) * 9 + tap]);
    }
    const int n2 = 9 * 16 * 64;
    if (t < n2){
      const int tap = t / (16 * 64);
      const int rem = t % (16 * 64);
      const int od = rem / 64, ic = rem % 64;
      const float v = (od < 10) ? Wpost[(od * 64 + ic) * 9 + tap] : 0.0f;
      WT2[t] = f2bf(v);
    }
    return;
  }
  // borders: one block per (b, py) 8-row slab
  __shared__ float slab[4096];
  const int rel = bid - 577;            // = b*64 + py
  const float* gp = gts + (size_t)rel * 4096;
#pragma unroll
  for (int it = 0; it < 4; ++it){
    const int id = it * 256 + tid;
    *(f32x4*)&slab[id * 4] = *(const f32x4*)&gp[id * 4];
  }
  __syncthreads();
  const int px = tid & 63, border = tid >> 6;   // border wave-uniform
  float s = 0.0f;
#pragma unroll
  for (int i = 0; i < 8; ++i){
    float v;
    if (border == 0)      v = slab[px * 8 + i];
    else if (border == 1) v = slab[7 * 512 + px * 8 + i];
    else if (border == 2) v = slab[i * 512 + px * 8];
    else                  v = slab[i * 512 + px * 8 + 7];
    v = ((v > 0.1f) && (v < 80.0f)) ? v : 0.0f;
    s += __logf(v + 1e-6f);
  }
  S[((size_t)rel * 64 + px) * 4 + border] = s;
}

// ---------------- NCHW fp32 -> [B*H*W][C] bf16 transpose ----------------
template<int C, int CH>
__global__ void k_transpose(const float* __restrict__ src, unsigned short* __restrict__ dst){
  constexpr int NCH = C / CH;
  const int bid = blockIdx.x;
  const int cg = bid % NCH;
  const int y  = (bid / NCH) % 64;
  const int b  = bid / (NCH * 64);
  __shared__ float lds[CH][65];
  const int t = threadIdx.x;
  const int x = t & 63, rg = t >> 6;
  const float* sp = src + ((size_t)b * C + (size_t)cg * CH) * 4096 + (size_t)y * 64;
#pragma unroll
  for (int r = rg; r < CH; r += 4) lds[r][x] = sp[(size_t)r * 4096 + x];
  __syncthreads();
  const int ox = t >> 2;
  const int oc0 = (t & 3) * 8;          // lane-quads cover contiguous 64B output lines
  unsigned short* dp = dst + ((size_t)b * 4096 + (size_t)y * 64 + ox) * C + cg * CH + oc0;
#pragma unroll
  for (int kk = 0; kk < CH / 32; ++kk){
    s16x8 v;
#pragma unroll
    for (int j = 0; j < 8; ++j) v[j] = (short)f2bf(lds[kk * 32 + oc0 + j][ox]);
    *(s16x8*)(dp + kk * 32) = v;
  }
}

// ---------------- GEMM1: att conv + sigmoid * depth ----------------
// 256 blocks x 512 threads. BM=512 (8 y-rows), halo 10 y-rows. 2-phase dbuf prefetch.
__global__ __launch_bounds__(512, 2) void k_gemm1(
    const unsigned short* __restrict__ featT,   // [B*4096][256]
    const unsigned short* __restrict__ WT1,     // [9][64][256]
    const float* __restrict__ batt,
    const float* __restrict__ depth,            // NCHW fp32 [B][64][64][64]
    unsigned short* __restrict__ adT)           // [B*4096][64]
{
  __shared__ unsigned short As[2][20480];   // 2 x 10*64 rows x 32 ic  (80 KB)
  __shared__ unsigned short Bs[2][18432];   // 2 x 576 rows x 32 ic    (72 KB)
  const int t = threadIdx.x;
  const int l = t & 63, w = t >> 6;
  const int b = blockIdx.x >> 3, ytile = blockIdx.x & 7;
  const int y0 = ytile * 8;
  const int fr = l & 15, g = l >> 4;

  f32x4 acc[4][4];
#pragma unroll
  for (int i = 0; i < 4; ++i)
#pragma unroll
    for (int j = 0; j < 4; ++j)
#pragma unroll
      for (int q = 0; q < 4; ++q) acc[i][j][q] = 0.0f;

  auto stageA = [&](int c, int d){
#pragma unroll
    for (int it2 = 0; it2 < 5; ++it2){
      const int it = it2 * 2 + (t >> 8);
      const int yy = y0 - 1 + it;
      const int x = (t >> 2) & 63, icg = t & 3;
      unsigned short* lp = &As[d][(it * 64 + x) * 32 + icg * 8];
      if (yy >= 0 && yy < 64){
        const unsigned short* gp = featT
            + ((size_t)(b * 4096 + yy * 64 + x)) * 256 + c * 32 + icg * 8;
        ASYNC16(gp, lp);
      } else {
        s16x8 z = {0,0,0,0,0,0,0,0};
        *(s16x8*)lp = z;
      }
    }
  };
  auto stageB = [&](int c, int d){
#pragma unroll
    for (int it = 0; it < 5; ++it){
      const int idx = it * 512 + t;
      if (idx < 2304){
        ASYNC16(WT1 + (size_t)(idx >> 2) * 256 + c * 32 + (idx & 3) * 8,
                &Bs[d][(idx >> 2) * 32 + (idx & 3) * 8]);
      }
    }
  };

  stageA(0, 0); stageB(0, 0);
  __syncthreads();

  for (int c = 0; c < 8; ++c){
    const int cur = c & 1;
    if (c < 7){ stageA(c + 1, cur ^ 1); stageB(c + 1, cur ^ 1); }
    const unsigned short* Ab = As[cur];
    const unsigned short* Bb = Bs[cur];
    for (int tap = 0; tap < 9; ++tap){
      const int dy = tap / 3 - 1, dx = tap % 3 - 1;
      s16x8 af[4], bfr[4];
#pragma unroll
      for (int i = 0; i < 4; ++i){
        const int xv = i * 16 + fr + dx;
        const bool valid = (xv >= 0) && (xv < 64);
        const int wr = valid ? ((w + dy + 1) * 64 + xv) : 0;
        s16x8 v = *(const s16x8*)&Ab[wr * 32 + g * 8];
        s16x8 z = {0,0,0,0,0,0,0,0};
        af[i] = valid ? v : z;
      }
#pragma unroll
      for (int j = 0; j < 4; ++j)
        bfr[j] = *(const s16x8*)&Bb[(tap * 64 + j * 16 + fr) * 32 + g * 8];
#pragma unroll
      for (int i = 0; i < 4; ++i)
#pragma unroll
        for (int j = 0; j < 4; ++j)
          acc[i][j] = __builtin_amdgcn_mfma_f32_16x16x32_bf16(af[i], bfr[j], acc[i][j], 0, 0, 0);
    }
    __syncthreads();
  }

  // epilogue: att = sigmoid(acc + b); adT = att * depth
  const int y = y0 + w;
#pragma unroll
  for (int j = 0; j < 4; ++j){
    const int oc = j * 16 + fr;
    const float bb = batt[oc];
    const float* dpt = depth + ((size_t)(b * 64 + oc)) * 4096 + (size_t)y * 64;
    unsigned short* op = adT + ((size_t)(b * 4096 + y * 64)) * 64 + oc;
#pragma unroll
    for (int i = 0; i < 4; ++i){
#pragma unroll
      for (int q = 0; q < 4; ++q){
        const int x = i * 16 + g * 4 + q;
        const float v = acc[i][j][q] + bb;
        const float att = 1.0f / (1.0f + __expf(-v));
        op[(size_t)x * 64] = f2bf(att * dpt[x]);
      }
    }
  }
}

// ---------------- GEMM2: post conv + fused smooth-L1 loss ----------------
DEVFN float sel4(f32x4 v, int i){
  const float ab = (i & 1) ? v[1] : v[0];
  const float cd = (i & 1) ? v[3] : v[2];
  return (i & 2) ? cd : ab;
}

__global__ __launch_bounds__(512, 2) void k_gemm2(
    const unsigned short* __restrict__ adT,     // [B*4096][64]
    const unsigned short* __restrict__ WT2,     // [9][16][64]
    const float* __restrict__ bpost,
    const f32x4* __restrict__ S,                // [B*4096] {Sn,Ss,Sw,Se}
    float* __restrict__ out)
{
  __shared__ unsigned short As[2][20480];   // 80 KB
  __shared__ unsigned short Bs[9216];       // full B resident (18 KB)
  __shared__ float ps[8];
  const int t = threadIdx.x;
  const int l = t & 63, w = t >> 6;
  const int b = blockIdx.x >> 3, ytile = blockIdx.x & 7;
  const int y0 = ytile * 8;
  const int fr = l & 15, g = l >> 4;

  f32x4 acc[4];
#pragma unroll
  for (int i = 0; i < 4; ++i)
#pragma unroll
    for (int q = 0; q < 4; ++q) acc[i][q] = 0.0f;

  auto stageA = [&](int c, int d){
#pragma unroll
    for (int it2 = 0; it2 < 5; ++it2){
      const int it = it2 * 2 + (t >> 8);
      const int yy = y0 - 1 + it;
      const int x = (t >> 2) & 63, icg = t & 3;
      unsigned short* lp = &As[d][(it * 64 + x) * 32 + icg * 8];
      if (yy >= 0 && yy < 64){
        const unsigned short* gp = adT
            + ((size_t)(b * 4096 + yy * 64 + x)) * 64 + c * 32 + icg * 8;
        ASYNC16(gp, lp);
      } else {
        s16x8 z = {0,0,0,0,0,0,0,0};
        *(s16x8*)lp = z;
      }
    }
  };
  // stage all of B once (144 rows x 64 ic)
#pragma unroll
  for (int it = 0; it < 3; ++it){
    const int idx = it * 512 + t;
    if (idx < 1152) ASYNC16(WT2 + (size_t)idx * 8, Bs + idx * 8);
  }
  stageA(0, 0);
  __syncthreads();

  for (int c = 0; c < 2; ++c){
    if (c == 0) stageA(1, 1);
    const unsigned short* Ab = As[c];
    for (int tap = 0; tap < 9; ++tap){
      const int dy = tap / 3 - 1, dx = tap % 3 - 1;
      s16x8 af[4];
#pragma unroll
      for (int i = 0; i < 4; ++i){
        const int xv = i * 16 + fr + dx;
        const bool valid = (xv >= 0) && (xv < 64);
        const int wr = valid ? ((w + dy + 1) * 64 + xv) : 0;
        s16x8 v = *(const s16x8*)&Ab[wr * 32 + g * 8];
        s16x8 z = {0,0,0,0,0,0,0,0};
        af[i] = valid ? v : z;
      }
      const s16x8 bfr = *(const s16x8*)&Bs[(tap * 16 + fr) * 64 + c * 32 + g * 8];
#pragma unroll
      for (int i = 0; i < 4; ++i)
        acc[i] = __builtin_amdgcn_mfma_f32_16x16x32_bf16(af[i], bfr, acc[i], 0, 0, 0);
    }
    __syncthreads();
  }

  // fused loss epilogue
  const unsigned aPack = (3u<<0)|(1u<<2)|(3u<<4)|(1u<<6)|(2u<<8)|(0u<<10)|(1u<<12)|(3u<<14)|(0u<<16)|(2u<<18);
  const unsigned bPack = (2u<<0)|(0u<<2)|(3u<<4)|(1u<<6)|(2u<<8)|(0u<<10)|(1u<<12)|(3u<<14)|(0u<<16)|(2u<<18);
  float lsum = 0.0f;
  const int y = y0 + w;
  if (fr < 10){
    const int od = fr;
    const int ai = (aPack >> (2 * od)) & 3;
    const int bi = (bPack >> (2 * od)) & 3;
    const bool xshift = (od & 1) == 0;
    const float bp = bpost[od];
#pragma unroll
    for (int i = 0; i < 4; ++i){
#pragma unroll
      for (int q = 0; q < 4; ++q){
        const int x = i * 16 + g * 4 + q;
        const size_t gm = (size_t)b * 4096 + (size_t)y * 64 + x;
        const f32x4 sa = S[gm];
        const bool nb = xshift ? (x < 63) : (y < 63);
        const size_t ga = xshift ? (nb ? gm + 1 : gm) : (nb ? gm + 64 : gm);
        const f32x4 sbv = S[ga];
        const float sbf = nb ? sel4(sbv, bi) : 0.0f;
        const float flow = (sel4(sa, ai) - sbf) * 0.125f;
        const float dv = acc[i][q] + bp - flow;
        const float adv = fabsf(dv);
        lsum += (adv < 0.01f) ? (50.0f * dv * dv) : (adv - 0.005f);
      }
    }
  }
#pragma unroll
  for (int off = 32; off > 0; off >>= 1) lsum += __shfl_down(lsum, off);
  if (l == 0) ps[w] = lsum;
  __syncthreads();
  if (t == 0){
    float s = 0.0f;
#pragma unroll
    for (int i = 0; i < 8; ++i) s += ps[i];
    atomicAdd(out, s * (1.0f / 1310720.0f));
  }
}

// ---------------- launch ----------------
extern "C" void kernel_launch(void* const* d_in, const int* in_sizes, int n_in,
                              void* d_out, int out_size, void* d_ws, size_t ws_size,
                              hipStream_t stream){
  const float* feat  = (const float*)d_in[0];
  const float* depth = (const float*)d_in[1];
  const float* gts   = (const float*)d_in[2];
  const float* Watt  = (const float*)d_in[3];
  const float* batt  = (const float*)d_in[4];
  const float* Wpost = (const float*)d_in[5];
  const float* bpost = (const float*)d_in[6];
  float* out = (float*)d_out;
  char* ws = (char*)d_ws;

  unsigned short* featT = (unsigned short*)ws;                                   // 67108864 B
  unsigned short* adT   = (unsigned short*)(ws + 67108864);                      // 16777216 B
  unsigned short* WT1   = (unsigned short*)(ws + 67108864 + 16777216);           // 294912 B
  unsigned short* WT2   = (unsigned short*)(ws + 67108864 + 16777216 + 294912);  // 18432 B
  float*          S     = (float*)(ws + 67108864 + 16777216 + 294912 + 18432);   // 2097152 B

  k_prep<<<1 + 576 + 2048, 256, 0, stream>>>(Watt, Wpost, gts, WT1, WT2, S, out);
  k_transpose<256, 128><<<32 * 64 * 2, 256, 0, stream>>>(feat, featT);
  k_gemm1<<<256, 512, 0, stream>>>(featT, WT1, batt, depth, adT);
  k_gemm2<<<256, 512, 0, stream>>>(adT, WT2, bpost, (const f32x4*)S, out);
}

// Round 3
// 93.323 us; speedup vs baseline: 1.5236x; 1.3078x over previous
//
#include <hip/hip_runtime.h>
#include <hip/hip_bf16.h>

// VarFlowLoss on MI355X (gfx950) — round 3
//   k_weights : W_att -> WT1 [9][64][256] bf16 ; W_post -> WT2 [9][16][64] bf16 (od padded)
//   k_gemm1   : fused transpose+conv GEMM. Reads feat NCHW fp32 directly, converts to bf16
//               in-register, ds_writes into XOR-swizzled LDS. Single-barrier dbuf pipeline.
//               Epilogue: att=sigmoid(.) ; adT = att * depth (depth read NCHW fp32).
//   k_borders : out=0 ; slab-coalesced patch border log-sums -> S
//   k_gemm2   : post conv + fused smooth-L1 loss (BM=512, dbuf A via glds, resident B)

typedef __attribute__((ext_vector_type(4))) float f32x4;
typedef __attribute__((ext_vector_type(8))) short s16x8;

#define DEVFN __device__ __forceinline__

DEVFN float bf2f(unsigned short u){
  unsigned int x = ((unsigned int)u) << 16;
  float f; __builtin_memcpy(&f, &x, 4); return f;
}
DEVFN unsigned short f2bf(float f){
  unsigned int x; __builtin_memcpy(&x, &f, 4);
  x += 0x7fffu + ((x >> 16) & 1u);   // RNE
  return (unsigned short)(x >> 16);
}

#define ASYNC16(gp, lp) __builtin_amdgcn_global_load_lds( \
    (const __attribute__((address_space(1))) unsigned int*)(gp), \
    (__attribute__((address_space(3))) unsigned int*)(lp), 16, 0, 0)

// ---------------- weights transform ----------------
__global__ void k_weights(const float* __restrict__ Watt, const float* __restrict__ Wpost,
                          unsigned short* __restrict__ WT1, unsigned short* __restrict__ WT2){
  const int t = blockIdx.x * 256 + threadIdx.x;
  const int n1 = 9 * 64 * 256;
  if (t < n1){
    const int tap = t / (64 * 256);
    const int rem = t % (64 * 256);
    const int oc = rem / 256, ic = rem % 256;
    WT1[t] = f2bf(Watt[(oc * 256 + ic) * 9 + tap]);
  }
  const int n2 = 9 * 16 * 64;
  if (t < n2){
    const int tap = t / (16 * 64);
    const int rem = t % (16 * 64);
    const int od = rem / 64, ic = rem % 64;
    const float v = (od < 10) ? Wpost[(od * 64 + ic) * 9 + tap] : 0.0f;
    WT2[t] = f2bf(v);
  }
}

// ---------------- borders: out=0 + patch border log-sums ----------------
__global__ void k_borders(const float* __restrict__ gts, float* __restrict__ S,
                          float* __restrict__ out){
  const int bid = blockIdx.x, tid = threadIdx.x;
  if (bid == 0 && tid == 0) *out = 0.0f;
  __shared__ float slab[4096];
  const int rel = bid;                  // = b*64 + py
  const float* gp = gts + (size_t)rel * 4096;
#pragma unroll
  for (int it = 0; it < 4; ++it){
    const int id = it * 256 + tid;
    *(f32x4*)&slab[id * 4] = *(const f32x4*)&gp[id * 4];
  }
  __syncthreads();
  const int px = tid & 63, border = tid >> 6;   // border wave-uniform
  float s = 0.0f;
#pragma unroll
  for (int i = 0; i < 8; ++i){
    float v;
    if (border == 0)      v = slab[px * 8 + i];
    else if (border == 1) v = slab[7 * 512 + px * 8 + i];
    else if (border == 2) v = slab[i * 512 + px * 8];
    else                  v = slab[i * 512 + px * 8 + 7];
    v = ((v > 0.1f) && (v < 80.0f)) ? v : 0.0f;
    s += __logf(v + 1e-6f);
  }
  S[((size_t)rel * 64 + px) * 4 + border] = s;
}

// ---------------- GEMM1: fused transpose + att conv + sigmoid * depth ----------------
// 256 blocks x 512 threads (8 waves). BM=512 (8 y-rows), halo 10 y-rows, BK=32, 8 chunks.
// A staged fp32->bf16 in-register into XOR-swizzled LDS; B via global_load_lds (linear).
__global__ __launch_bounds__(512, 2) void k_gemm1(
    const float* __restrict__ feat,             // NCHW fp32 [B][256][64][64]
    const unsigned short* __restrict__ WT1,     // [9][64][256]
    const float* __restrict__ batt,
    const float* __restrict__ depth,            // NCHW fp32 [B][64][64][64]
    unsigned short* __restrict__ adT)           // [B*4096][64]
{
  __shared__ unsigned short As[2][640 * 32];   // 2 x (10 yy * 64 x) rows x 32 ic  (80 KB), swizzled
  __shared__ unsigned short Bs[2][576 * 32];   // 2 x 576 rows x 32 ic             (72 KB), linear
  const int t = threadIdx.x;
  const int l = t & 63, w = t >> 6;
  const int b = blockIdx.x >> 3, ytile = blockIdx.x & 7;
  const int y0 = ytile * 8;
  const int fr = l & 15, g = l >> 4;
  const int x = t & 63, seg = t >> 6;
  const int sx = (x >> 1) & 3;                 // write-side swizzle nibble

  f32x4 acc[4][4];
#pragma unroll
  for (int i = 0; i < 4; ++i)
#pragma unroll
    for (int j = 0; j < 4; ++j)
#pragma unroll
      for (int q = 0; q < 4; ++q) acc[i][j][q] = 0.0f;

  // load 40 fp32 of A-chunk c into regs (5 combos x 8 ic), coalesced along x
  auto loadA = [&](int c, float* r, int j0, int j1){
#pragma unroll
    for (int j = 0; j < 5; ++j){
      if (j < j0 || j >= j1) continue;
      const int idx = seg + j * 8;             // 0..39
      const int yy = idx >> 2;                 // 0..9
      const int icg = idx & 3;
      const int yr = y0 - 1 + yy;
      if (yr >= 0 && yr < 64){
        const float* gp = feat + ((size_t)(b * 256 + c * 32 + icg * 8)) * 4096
                               + (size_t)yr * 64 + x;
#pragma unroll
        for (int e = 0; e < 8; ++e) r[j * 8 + e] = gp[(size_t)e * 4096];
      } else {
#pragma unroll
        for (int e = 0; e < 8; ++e) r[j * 8 + e] = 0.0f;
      }
    }
  };
  auto writeA = [&](int d, const float* r, int j0, int j1){
#pragma unroll
    for (int j = 0; j < 5; ++j){
      if (j < j0 || j >= j1) continue;
      const int idx = seg + j * 8;
      const int yy = idx >> 2, icg = idx & 3;
      s16x8 v;
#pragma unroll
      for (int e = 0; e < 8; ++e) v[e] = (short)f2bf(r[j * 8 + e]);
      *(s16x8*)&As[d][(yy * 64 + x) * 32 + ((icg ^ sx) * 8)] = v;
    }
  };
  auto stageB = [&](int c, int d){
#pragma unroll
    for (int it = 0; it < 5; ++it){
      const int idx = it * 512 + t;
      if (idx < 2304){
        ASYNC16(WT1 + (size_t)(idx >> 2) * 256 + c * 32 + (idx & 3) * 8,
                &Bs[d][(idx >> 2) * 32 + (idx & 3) * 8]);
      }
    }
  };
  auto compute = [&](int cur, int t0, int t1){
    for (int tap = t0; tap < t1; ++tap){
      const int dy = tap / 3 - 1, dx = tap % 3 - 1;
      const int st = ((fr + dx) & 7) >> 1;     // read-side swizzle (uniform over i)
      const int grp = (g ^ st) * 8;
      s16x8 af[4], bfr[4];
#pragma unroll
      for (int i = 0; i < 4; ++i){
        const int xv = i * 16 + fr + dx;
        const bool valid = (xv >= 0) && (xv < 64);
        const int row = (w + dy + 1) * 64 + (valid ? xv : 0);
        s16x8 v = *(const s16x8*)&As[cur][row * 32 + grp];
        s16x8 z = {0,0,0,0,0,0,0,0};
        af[i] = valid ? v : z;
      }
#pragma unroll
      for (int j = 0; j < 4; ++j)
        bfr[j] = *(const s16x8*)&Bs[cur][(tap * 64 + j * 16 + fr) * 32 + g * 8];
#pragma unroll
      for (int i = 0; i < 4; ++i)
#pragma unroll
        for (int j = 0; j < 4; ++j)
          acc[i][j] = __builtin_amdgcn_mfma_f32_16x16x32_bf16(af[i], bfr[j], acc[i][j], 0, 0, 0);
    }
  };

  // prologue: chunk 0
  float r0[40];
  stageB(0, 0);
  loadA(0, r0, 0, 5);
  writeA(0, r0, 0, 5);
  __syncthreads();

  float r1[40];
  for (int c = 0; c < 8; ++c){
    const int cur = c & 1;
    if (c < 7){
      stageB(c + 1, cur ^ 1);        // async -> drained by end-of-iter barrier
      loadA(c + 1, r1, 0, 5);        // reg loads, counted-vmcnt waits at writeA
    }
    compute(cur, 0, 6);              // taps 0..5 hide load latency
    if (c < 7) writeA(cur ^ 1, r1, 0, 3);
    compute(cur, 6, 9);              // taps 6..8
    if (c < 7) writeA(cur ^ 1, r1, 3, 5);
    __syncthreads();
  }

  // epilogue: att = sigmoid(acc + b); adT = att * depth
  const int y = y0 + w;
#pragma unroll
  for (int j = 0; j < 4; ++j){
    const int oc = j * 16 + fr;
    const float bb = batt[oc];
    const float* dpt = depth + ((size_t)(b * 64 + oc)) * 4096 + (size_t)y * 64;
    unsigned short* op = adT + ((size_t)(b * 4096 + y * 64)) * 64 + oc;
#pragma unroll
    for (int i = 0; i < 4; ++i){
#pragma unroll
      for (int q = 0; q < 4; ++q){
        const int xo = i * 16 + g * 4 + q;
        const float v = acc[i][j][q] + bb;
        const float att = 1.0f / (1.0f + __expf(-v));
        op[(size_t)xo * 64] = f2bf(att * dpt[xo]);
      }
    }
  }
}

// ---------------- GEMM2: post conv + fused smooth-L1 loss ----------------
DEVFN float sel4(f32x4 v, int i){
  const float ab = (i & 1) ? v[1] : v[0];
  const float cd = (i & 1) ? v[3] : v[2];
  return (i & 2) ? cd : ab;
}

__global__ __launch_bounds__(512, 2) void k_gemm2(
    const unsigned short* __restrict__ adT,     // [B*4096][64]
    const unsigned short* __restrict__ WT2,     // [9][16][64]
    const float* __restrict__ bpost,
    const f32x4* __restrict__ S,                // [B*4096] {Sn,Ss,Sw,Se}
    float* __restrict__ out)
{
  __shared__ unsigned short As[2][20480];   // 80 KB
  __shared__ unsigned short Bs[9216];       // full B resident (18 KB)
  __shared__ float ps[8];
  const int t = threadIdx.x;
  const int l = t & 63, w = t >> 6;
  const int b = blockIdx.x >> 3, ytile = blockIdx.x & 7;
  const int y0 = ytile * 8;
  const int fr = l & 15, g = l >> 4;

  f32x4 acc[4];
#pragma unroll
  for (int i = 0; i < 4; ++i)
#pragma unroll
    for (int q = 0; q < 4; ++q) acc[i][q] = 0.0f;

  auto stageA = [&](int c, int d){
#pragma unroll
    for (int it2 = 0; it2 < 5; ++it2){
      const int it = it2 * 2 + (t >> 8);
      const int yy = y0 - 1 + it;
      const int xx = (t >> 2) & 63, icg = t & 3;
      unsigned short* lp = &As[d][(it * 64 + xx) * 32 + icg * 8];
      if (yy >= 0 && yy < 64){
        const unsigned short* gp = adT
            + ((size_t)(b * 4096 + yy * 64 + xx)) * 64 + c * 32 + icg * 8;
        ASYNC16(gp, lp);
      } else {
        s16x8 z = {0,0,0,0,0,0,0,0};
        *(s16x8*)lp = z;
      }
    }
  };
  // stage all of B once (144 rows x 64 ic)
#pragma unroll
  for (int it = 0; it < 3; ++it){
    const int idx = it * 512 + t;
    if (idx < 1152) ASYNC16(WT2 + (size_t)idx * 8, Bs + idx * 8);
  }
  stageA(0, 0);
  __syncthreads();

  for (int c = 0; c < 2; ++c){
    if (c == 0) stageA(1, 1);
    const unsigned short* Ab = As[c];
    for (int tap = 0; tap < 9; ++tap){
      const int dy = tap / 3 - 1, dx = tap % 3 - 1;
      s16x8 af[4];
#pragma unroll
      for (int i = 0; i < 4; ++i){
        const int xv = i * 16 + fr + dx;
        const bool valid = (xv >= 0) && (xv < 64);
        const int wr = valid ? ((w + dy + 1) * 64 + xv) : 0;
        s16x8 v = *(const s16x8*)&Ab[wr * 32 + g * 8];
        s16x8 z = {0,0,0,0,0,0,0,0};
        af[i] = valid ? v : z;
      }
      const s16x8 bfr = *(const s16x8*)&Bs[(tap * 16 + fr) * 64 + c * 32 + g * 8];
#pragma unroll
      for (int i = 0; i < 4; ++i)
        acc[i] = __builtin_amdgcn_mfma_f32_16x16x32_bf16(af[i], bfr, acc[i], 0, 0, 0);
    }
    __syncthreads();
  }

  // fused loss epilogue
  const unsigned aPack = (3u<<0)|(1u<<2)|(3u<<4)|(1u<<6)|(2u<<8)|(0u<<10)|(1u<<12)|(3u<<14)|(0u<<16)|(2u<<18);
  const unsigned bPack = (2u<<0)|(0u<<2)|(3u<<4)|(1u<<6)|(2u<<8)|(0u<<10)|(1u<<12)|(3u<<14)|(0u<<16)|(2u<<18);
  float lsum = 0.0f;
  const int y = y0 + w;
  if (fr < 10){
    const int od = fr;
    const int ai = (aPack >> (2 * od)) & 3;
    const int bi = (bPack >> (2 * od)) & 3;
    const bool xshift = (od & 1) == 0;
    const float bp = bpost[od];
#pragma unroll
    for (int i = 0; i < 4; ++i){
#pragma unroll
      for (int q = 0; q < 4; ++q){
        const int xo = i * 16 + g * 4 + q;
        const size_t gm = (size_t)b * 4096 + (size_t)y * 64 + xo;
        const f32x4 sa = S[gm];
        const bool nb = xshift ? (xo < 63) : (y < 63);
        const size_t ga = xshift ? (nb ? gm + 1 : gm) : (nb ? gm + 64 : gm);
        const f32x4 sbv = S[ga];
        const float sbf = nb ? sel4(sbv, bi) : 0.0f;
        const float flow = (sel4(sa, ai) - sbf) * 0.125f;
        const float dv = acc[i][q] + bp - flow;
        const float adv = fabsf(dv);
        lsum += (adv < 0.01f) ? (50.0f * dv * dv) : (adv - 0.005f);
      }
    }
  }
#pragma unroll
  for (int off = 32; off > 0; off >>= 1) lsum += __shfl_down(lsum, off);
  if (l == 0) ps[w] = lsum;
  __syncthreads();
  if (t == 0){
    float s = 0.0f;
#pragma unroll
    for (int i = 0; i < 8; ++i) s += ps[i];
    atomicAdd(out, s * (1.0f / 1310720.0f));
  }
}

// ---------------- launch ----------------
extern "C" void kernel_launch(void* const* d_in, const int* in_sizes, int n_in,
                              void* d_out, int out_size, void* d_ws, size_t ws_size,
                              hipStream_t stream){
  const float* feat  = (const float*)d_in[0];
  const float* depth = (const float*)d_in[1];
  const float* gts   = (const float*)d_in[2];
  const float* Watt  = (const float*)d_in[3];
  const float* batt  = (const float*)d_in[4];
  const float* Wpost = (const float*)d_in[5];
  const float* bpost = (const float*)d_in[6];
  float* out = (float*)d_out;
  char* ws = (char*)d_ws;

  unsigned short* adT = (unsigned short*)ws;                       // 16777216 B
  unsigned short* WT1 = (unsigned short*)(ws + 16777216);          // 294912 B
  unsigned short* WT2 = (unsigned short*)(ws + 16777216 + 294912); // 18432 B
  float*          S   = (float*)(ws + 16777216 + 294912 + 18432);  // 2097152 B

  k_weights<<<576, 256, 0, stream>>>(Watt, Wpost, WT1, WT2);
  k_gemm1<<<256, 512, 0, stream>>>(feat, WT1, batt, depth, adT);
  k_borders<<<2048, 256, 0, stream>>>(gts, S, out);
  k_gemm2<<<256, 512, 0, stream>>>(adT, WT2, bpost, (const f32x4*)S, out);
}

// Round 4
// 89.034 us; speedup vs baseline: 1.5970x; 1.0482x over previous
//
#include <hip/hip_runtime.h>
#include <hip/hip_bf16.h>

// VarFlowLoss on MI355X (gfx950) — round 4
//   k_weights : W_att -> WT1 [9][64][256] bf16 ; W_post -> WT2 [9][16][64] bf16 (od padded)
//   k_gemm1   : fused transpose+conv GEMM. BM=512, 8 waves, single-buffered A (reg-staged
//               fp32->bf16, zero-padded x-halo columns -> no edge cndmask), dbuf B via
//               source-swizzled global_load_lds. All LDS accesses 2-way-or-free bank-wise.
//   k_borders : out=0 ; slab-coalesced patch border log-sums -> S
//   k_gemm2   : post conv + fused smooth-L1 loss (swizzled A/B, dbuf A via glds)

typedef __attribute__((ext_vector_type(4))) float f32x4;
typedef __attribute__((ext_vector_type(8))) short s16x8;

#define DEVFN __device__ __forceinline__

DEVFN float bf2f(unsigned short u){
  unsigned int x = ((unsigned int)u) << 16;
  float f; __builtin_memcpy(&f, &x, 4); return f;
}
DEVFN unsigned short f2bf(float f){
  unsigned int x; __builtin_memcpy(&x, &f, 4);
  x += 0x7fffu + ((x >> 16) & 1u);   // RNE
  return (unsigned short)(x >> 16);
}

#define ASYNC16(gp, lp) __builtin_amdgcn_global_load_lds( \
    (const __attribute__((address_space(1))) unsigned int*)(gp), \
    (__attribute__((address_space(3))) unsigned int*)(lp), 16, 0, 0)

// ---------------- weights transform ----------------
__global__ void k_weights(const float* __restrict__ Watt, const float* __restrict__ Wpost,
                          unsigned short* __restrict__ WT1, unsigned short* __restrict__ WT2){
  const int t = blockIdx.x * 256 + threadIdx.x;
  const int n1 = 9 * 64 * 256;
  if (t < n1){
    const int tap = t / (64 * 256);
    const int rem = t % (64 * 256);
    const int oc = rem / 256, ic = rem % 256;
    WT1[t] = f2bf(Watt[(oc * 256 + ic) * 9 + tap]);
  }
  const int n2 = 9 * 16 * 64;
  if (t < n2){
    const int tap = t / (16 * 64);
    const int rem = t % (16 * 64);
    const int od = rem / 64, ic = rem % 64;
    const float v = (od < 10) ? Wpost[(od * 64 + ic) * 9 + tap] : 0.0f;
    WT2[t] = f2bf(v);
  }
}

// ---------------- borders: out=0 + patch border log-sums ----------------
__global__ void k_borders(const float* __restrict__ gts, float* __restrict__ S,
                          float* __restrict__ out){
  const int bid = blockIdx.x, tid = threadIdx.x;
  if (bid == 0 && tid == 0) *out = 0.0f;
  __shared__ float slab[4096];
  const int rel = bid;                  // = b*64 + py
  const float* gp = gts + (size_t)rel * 4096;
#pragma unroll
  for (int it = 0; it < 4; ++it){
    const int id = it * 256 + tid;
    *(f32x4*)&slab[id * 4] = *(const f32x4*)&gp[id * 4];
  }
  __syncthreads();
  const int px = tid & 63, border = tid >> 6;   // border wave-uniform
  float s = 0.0f;
#pragma unroll
  for (int i = 0; i < 8; ++i){
    float v;
    if (border == 0)      v = slab[px * 8 + i];
    else if (border == 1) v = slab[7 * 512 + px * 8 + i];
    else if (border == 2) v = slab[i * 512 + px * 8];
    else                  v = slab[i * 512 + px * 8 + 7];
    v = ((v > 0.1f) && (v < 80.0f)) ? v : 0.0f;
    s += __logf(v + 1e-6f);
  }
  S[((size_t)rel * 64 + px) * 4 + border] = s;
}

// ---------------- GEMM1: fused transpose + att conv + sigmoid * depth ----------------
// 256 blocks x 512 threads (8 waves). BM=512, BK=32, 8 chunks.
// A: single-buffered [10 yy][72 xp][32 ic] with zero columns xp=0,65; reg-staged (T14).
// B: double-buffered [576 rows][32 ic] via source-swizzled global_load_lds.
__global__ __launch_bounds__(512, 2) void k_gemm1(
    const float* __restrict__ feat,             // NCHW fp32 [B][256][64][64]
    const unsigned short* __restrict__ WT1,     // [9][64][256]
    const float* __restrict__ batt,
    const float* __restrict__ depth,            // NCHW fp32 [B][64][64][64]
    unsigned short* __restrict__ adT)           // [B*4096][64]
{
  __shared__ unsigned short As[720 * 32];      // 10*72 rows x 32 ic  (45 KB), XOR-swizzled
  __shared__ unsigned short Bs[2][576 * 32];   // 2 x 36 KB, XOR-swizzled via source
  const int t = threadIdx.x;
  const int l = t & 63, w = t >> 6;
  const int b = blockIdx.x >> 3, ytile = blockIdx.x & 7;
  const int y0 = ytile * 8;
  const int fr = l & 15, g = l >> 4;
  const int x = t & 63, seg = t >> 6;

  f32x4 acc[4][4];
#pragma unroll
  for (int i = 0; i < 4; ++i)
#pragma unroll
    for (int j = 0; j < 4; ++j)
#pragma unroll
      for (int q = 0; q < 4; ++q) acc[i][j][q] = 0.0f;

  // zero the x-halo columns once (A is single-buffered; interior rewritten per chunk)
  if (t < 80){
    const int yy = t >> 3, k = t & 7;
    const int xp = (k & 1) ? 65 : 0;
    s16x8 z = {0,0,0,0,0,0,0,0};
    *(s16x8*)&As[(yy * 72 + xp) * 32 + (k >> 1) * 8] = z;
  }

  auto stageB = [&](int c, int d){
#pragma unroll
    for (int it = 0; it < 5; ++it){
      const int idx = it * 512 + t;
      if (idx < 2304){
        const int row = idx >> 2;
        const int sg = (idx & 3) ^ ((row >> 1) & 3);   // source-slot swizzle
        ASYNC16(WT1 + (size_t)row * 256 + c * 32 + sg * 8, &Bs[d][(size_t)idx * 8]);
      }
    }
  };
  auto loadA = [&](int c, float* rr){
#pragma unroll
    for (int j = 0; j < 5; ++j){
      const int idx = seg + j * 8;                 // 0..39
      const int yy = idx >> 2, icg = idx & 3;
      const int yr = y0 - 1 + yy;
      if (yr >= 0 && yr < 64){
        const float* gp = feat + ((size_t)(b * 256 + c * 32 + icg * 8)) * 4096
                               + (size_t)yr * 64 + x;
#pragma unroll
        for (int e = 0; e < 8; ++e) rr[j * 8 + e] = gp[(size_t)e * 4096];
      } else {
#pragma unroll
        for (int e = 0; e < 8; ++e) rr[j * 8 + e] = 0.0f;
      }
    }
  };
  auto cvtA = [&](const float* rr, s16x8* vA){
#pragma unroll
    for (int j = 0; j < 5; ++j)
#pragma unroll
      for (int e = 0; e < 8; ++e) vA[j][e] = (short)f2bf(rr[j * 8 + e]);
  };
  auto writeA = [&](const s16x8* vA){
    const int xp = x + 1;
    const int sx = (xp >> 1) & 3;
#pragma unroll
    for (int j = 0; j < 5; ++j){
      const int idx = seg + j * 8;
      const int yy = idx >> 2, icg = idx & 3;
      *(s16x8*)&As[(yy * 72 + xp) * 32 + ((icg ^ sx) * 8)] = vA[j];
    }
  };
  auto compute = [&](const unsigned short* Bb, int t0, int t1){
    const int slotB = (g ^ ((fr >> 1) & 3)) * 8;
    for (int tap = t0; tap < t1; ++tap){
      const int dy = tap / 3 - 1, dxp = tap % 3;     // dx+1
      const int r = fr + dxp;                        // xp of fragment base
      const int slotA = (g ^ ((r >> 1) & 3)) * 8;
      const int rowb = ((w + dy + 1) * 72 + r) * 32 + slotA;
      s16x8 af[4], bfr[4];
#pragma unroll
      for (int i = 0; i < 4; ++i) af[i] = *(const s16x8*)&As[rowb + i * 512];
#pragma unroll
      for (int j = 0; j < 4; ++j)
        bfr[j] = *(const s16x8*)&Bb[(tap * 64 + j * 16 + fr) * 32 + slotB];
#pragma unroll
      for (int i = 0; i < 4; ++i)
#pragma unroll
        for (int j = 0; j < 4; ++j)
          acc[i][j] = __builtin_amdgcn_mfma_f32_16x16x32_bf16(af[i], bfr[j], acc[i][j], 0, 0, 0);
    }
  };

  // prologue: chunk 0
  float rr[40]; s16x8 vA[5];
  stageB(0, 0);
  loadA(0, rr);
  cvtA(rr, vA);
  writeA(vA);
  __syncthreads();

  for (int c = 0; c < 8; ++c){
    const int cur = c & 1;
    if (c < 7){ stageB(c + 1, cur ^ 1); loadA(c + 1, rr); }
    compute(Bs[cur], 0, 5);              // taps 0..4 hide load latency
    if (c < 7) cvtA(rr, vA);
    compute(Bs[cur], 5, 9);              // taps 5..8
    __syncthreads();                     // readers done with As / Bs[cur]
    if (c < 7) writeA(vA);
    __syncthreads();                     // As ready (Bs[cur^1] drained by barrier)
  }

  // epilogue: att = sigmoid(acc + b); adT = att * depth
  const int y = y0 + w;
#pragma unroll
  for (int j = 0; j < 4; ++j){
    const int oc = j * 16 + fr;
    const float bb = batt[oc];
    const float* dpt = depth + ((size_t)(b * 64 + oc)) * 4096 + (size_t)y * 64;
    unsigned short* op = adT + ((size_t)(b * 4096 + y * 64)) * 64 + oc;
#pragma unroll
    for (int i = 0; i < 4; ++i){
#pragma unroll
      for (int q = 0; q < 4; ++q){
        const int xo = i * 16 + g * 4 + q;
        const float v = acc[i][j][q] + bb;
        const float att = 1.0f / (1.0f + __expf(-v));
        op[(size_t)xo * 64] = f2bf(att * dpt[xo]);
      }
    }
  }
}

// ---------------- GEMM2: post conv + fused smooth-L1 loss ----------------
DEVFN float sel4(f32x4 v, int i){
  const float ab = (i & 1) ? v[1] : v[0];
  const float cd = (i & 1) ? v[3] : v[2];
  return (i & 2) ? cd : ab;
}

__global__ __launch_bounds__(512, 2) void k_gemm2(
    const unsigned short* __restrict__ adT,     // [B*4096][64]
    const unsigned short* __restrict__ WT2,     // [9][16][64]
    const float* __restrict__ bpost,
    const f32x4* __restrict__ S,                // [B*4096] {Sn,Ss,Sw,Se}
    float* __restrict__ out)
{
  __shared__ unsigned short As[2][20480];   // 80 KB, source-swizzled
  __shared__ unsigned short Bs[9216];       // full B resident (18 KB), source-swizzled
  __shared__ float ps[8];
  const int t = threadIdx.x;
  const int l = t & 63, w = t >> 6;
  const int b = blockIdx.x >> 3, ytile = blockIdx.x & 7;
  const int y0 = ytile * 8;
  const int fr = l & 15, g = l >> 4;

  f32x4 acc[4];
#pragma unroll
  for (int i = 0; i < 4; ++i)
#pragma unroll
    for (int q = 0; q < 4; ++q) acc[i][q] = 0.0f;

  auto stageA = [&](int c, int d){
#pragma unroll
    for (int it2 = 0; it2 < 5; ++it2){
      const int it = it2 * 2 + (t >> 8);
      const int yy = y0 - 1 + it;
      const int xx = (t >> 2) & 63, icg = t & 3;
      unsigned short* lp = &As[d][(it * 64 + xx) * 32 + icg * 8];
      if (yy >= 0 && yy < 64){
        const int sg = icg ^ ((xx >> 1) & 3);        // source-slot swizzle
        const unsigned short* gp = adT
            + ((size_t)(b * 4096 + yy * 64 + xx)) * 64 + c * 32 + sg * 8;
        ASYNC16(gp, lp);
      } else {
        s16x8 z = {0,0,0,0,0,0,0,0};
        *(s16x8*)lp = z;
      }
    }
  };
  // stage all of B once (144 rows x 128B), 16B slots XOR'd by row&7
#pragma unroll
  for (int it = 0; it < 3; ++it){
    const int idx = it * 512 + t;
    if (idx < 1152){
      const int row = idx >> 3, p = idx & 7;
      const int sg = p ^ (row & 7);
      ASYNC16(WT2 + (size_t)row * 64 + sg * 8, Bs + (size_t)idx * 8);
    }
  }
  stageA(0, 0);
  __syncthreads();

  for (int c = 0; c < 2; ++c){
    if (c == 0) stageA(1, 1);
    const unsigned short* Ab = As[c];
    const int pB = ((c * 4 + g) ^ (fr & 7)) * 8;
    for (int tap = 0; tap < 9; ++tap){
      const int dy = tap / 3 - 1, dx = tap % 3 - 1;
      s16x8 af[4];
#pragma unroll
      for (int i = 0; i < 4; ++i){
        const int xv = i * 16 + fr + dx;
        const bool valid = (xv >= 0) && (xv < 64);
        const int xw = valid ? xv : 0;
        const int slot = (g ^ ((xw >> 1) & 3)) * 8;
        s16x8 v = *(const s16x8*)&Ab[((w + dy + 1) * 64 + xw) * 32 + slot];
        s16x8 z = {0,0,0,0,0,0,0,0};
        af[i] = valid ? v : z;
      }
      const s16x8 bfr = *(const s16x8*)&Bs[(tap * 16 + fr) * 64 + pB];
#pragma unroll
      for (int i = 0; i < 4; ++i)
        acc[i] = __builtin_amdgcn_mfma_f32_16x16x32_bf16(af[i], bfr, acc[i], 0, 0, 0);
    }
    __syncthreads();
  }

  // fused loss epilogue
  const unsigned aPack = (3u<<0)|(1u<<2)|(3u<<4)|(1u<<6)|(2u<<8)|(0u<<10)|(1u<<12)|(3u<<14)|(0u<<16)|(2u<<18);
  const unsigned bPack = (2u<<0)|(0u<<2)|(3u<<4)|(1u<<6)|(2u<<8)|(0u<<10)|(1u<<12)|(3u<<14)|(0u<<16)|(2u<<18);
  float lsum = 0.0f;
  const int y = y0 + w;
  if (fr < 10){
    const int od = fr;
    const int ai = (aPack >> (2 * od)) & 3;
    const int bi = (bPack >> (2 * od)) & 3;
    const bool xshift = (od & 1) == 0;
    const float bp = bpost[od];
#pragma unroll
    for (int i = 0; i < 4; ++i){
#pragma unroll
      for (int q = 0; q < 4; ++q){
        const int xo = i * 16 + g * 4 + q;
        const size_t gm = (size_t)b * 4096 + (size_t)y * 64 + xo;
        const f32x4 sa = S[gm];
        const bool nb = xshift ? (xo < 63) : (y < 63);
        const size_t ga = xshift ? (nb ? gm + 1 : gm) : (nb ? gm + 64 : gm);
        const f32x4 sbv = S[ga];
        const float sbf = nb ? sel4(sbv, bi) : 0.0f;
        const float flow = (sel4(sa, ai) - sbf) * 0.125f;
        const float dv = acc[i][q] + bp - flow;
        const float adv = fabsf(dv);
        lsum += (adv < 0.01f) ? (50.0f * dv * dv) : (adv - 0.005f);
      }
    }
  }
#pragma unroll
  for (int off = 32; off > 0; off >>= 1) lsum += __shfl_down(lsum, off);
  if (l == 0) ps[w] = lsum;
  __syncthreads();
  if (t == 0){
    float s = 0.0f;
#pragma unroll
    for (int i = 0; i < 8; ++i) s += ps[i];
    atomicAdd(out, s * (1.0f / 1310720.0f));
  }
}

// ---------------- launch ----------------
extern "C" void kernel_launch(void* const* d_in, const int* in_sizes, int n_in,
                              void* d_out, int out_size, void* d_ws, size_t ws_size,
                              hipStream_t stream){
  const float* feat  = (const float*)d_in[0];
  const float* depth = (const float*)d_in[1];
  const float* gts   = (const float*)d_in[2];
  const float* Watt  = (const float*)d_in[3];
  const float* batt  = (const float*)d_in[4];
  const float* Wpost = (const float*)d_in[5];
  const float* bpost = (const float*)d_in[6];
  float* out = (float*)d_out;
  char* ws = (char*)d_ws;

  unsigned short* adT = (unsigned short*)ws;                       // 16777216 B
  unsigned short* WT1 = (unsigned short*)(ws + 16777216);          // 294912 B
  unsigned short* WT2 = (unsigned short*)(ws + 16777216 + 294912); // 18432 B
  float*          S   = (float*)(ws + 16777216 + 294912 + 18432);  // 2097152 B

  k_weights<<<576, 256, 0, stream>>>(Watt, Wpost, WT1, WT2);
  k_gemm1<<<256, 512, 0, stream>>>(feat, WT1, batt, depth, adT);
  k_borders<<<2048, 256, 0, stream>>>(gts, S, out);
  k_gemm2<<<256, 512, 0, stream>>>(adT, WT2, bpost, (const f32x4*)S, out);
}